// Round 1
// baseline (403.144 us; speedup 1.0000x reference)
//
#include <hip/hip_runtime.h>
#include <hip/hip_fp16.h>
#include <stdint.h>

typedef _Float16 half_t;
typedef __attribute__((ext_vector_type(8))) _Float16 half8;   // MFMA A/B frag (4 VGPRs)
typedef __attribute__((ext_vector_type(16))) float f32x16;    // 32x32 MFMA C/D frag
typedef __attribute__((ext_vector_type(4)))  float float4v;

#define BM 128
#define BN 128
#define BK 64   // 8 chunks of 8 halves (16 B) per row

// ---------------------------------------------------------------------------
// Single fused kernel: quantize-on-stage + GEMM. NO workspace, NO second
// kernel, NO branch on ws_size.
//
// Rationale (R0 post-mortem): the previous two-kernel d_ws version failed the
// POST-timing check with self-consistent wrong outputs (tripwire passed,
// replays == fresh launches, absmax 145 ~ max|A.B| of a tile) while the
// pre-timing check passed. That signature is persistent-state dependence, and
// the only call-variant state in kernel_launch was the ws_size branch + the
// cross-kernel q intermediate in harness-poisonable d_ws. This version is
// stateless per call: fp32 tile loads -> f16 RNE cvt (== reference e5m10
// quantize, denormals included) -> ds_write_b128, then MFMA.
//
// C[m][n] = sum_k q(A[m][k])*q(B[n][k]) + q(bias[n]).  Both operands
// K-contiguous. 128x128 tile, BK=64, 4 waves (2x2 of 64x64),
// mfma_f32_32x32x16_f16, XOR chunk swizzle on LDS k-chunks.
// Block swizzle: block b -> XCD b&7 (round-robin assumption, perf-only);
// each XCD owns a 4-wide bn strip for B L2/LLC locality.
// ---------------------------------------------------------------------------
__global__ __launch_bounds__(256)
void gemm_qf16_fused(const float* __restrict__ A, const float* __restrict__ B,
                     const float* __restrict__ bias, float* __restrict__ C,
                     int M, int N, int K) {
    __shared__ half_t sA[BM * BK];   // 16 KB
    __shared__ half_t sB[BN * BK];   // 16 KB

    const int t    = threadIdx.x;
    const int lane = t & 63;
    const int wave = t >> 6;
    const int wm   = (wave >> 1) * 64;
    const int wn   = (wave & 1) * 64;

    // XCD-aware 1-D -> 2-D block swizzle (specialized for the 32x32 grid)
    const int nbx = N / BN, nby = M / BM;
    int bxi, byi;
    {
        const int b = blockIdx.x;
        if (nbx == 32 && nby == 32) {
            const int xcd = b & 7;
            const int s   = b >> 3;
            bxi = xcd * 4 + (s & 3);   // bn strip of 4 per XCD
            byi = s >> 2;
        } else {
            bxi = b % nbx;
            byi = b / nbx;
        }
    }
    const int bm = byi * BM;
    const int bn = bxi * BN;

    // staging: 1024 16B-chunks (f16) per matrix, 4 per thread; chunk index c:
    // row = c>>3, LDS pos = c&7, global k-chunk = (c&7) ^ (row&7)
    int srow[4], skc[4];
    #pragma unroll
    for (int s = 0; s < 4; ++s) {
        const int c = t + 256 * s;
        srow[s] = c >> 3;
        skc[s]  = (c & 7) ^ (srow[s] & 7);
    }

    f32x16 acc[2][2] = {};

    const int ml = lane & 31;   // m (or n) within 32-tile
    const int kg = lane >> 5;   // which 8-k half of the MFMA's K=16
    const int sw = ml & 7;      // row component of the XOR swizzle

    for (int k0 = 0; k0 < K; k0 += BK) {
        #pragma unroll
        for (int s = 0; s < 4; ++s) {
            const long ga = (long)(bm + srow[s]) * K + k0 + skc[s] * 8;
            const long gb = (long)(bn + srow[s]) * K + k0 + skc[s] * 8;
            float4v a0 = *(const float4v*)(A + ga);
            float4v a1 = *(const float4v*)(A + ga + 4);
            float4v b0 = *(const float4v*)(B + gb);
            float4v b1 = *(const float4v*)(B + gb + 4);
            half8 ha, hb;
            ha[0]=(half_t)a0[0]; ha[1]=(half_t)a0[1]; ha[2]=(half_t)a0[2]; ha[3]=(half_t)a0[3];
            ha[4]=(half_t)a1[0]; ha[5]=(half_t)a1[1]; ha[6]=(half_t)a1[2]; ha[7]=(half_t)a1[3];
            hb[0]=(half_t)b0[0]; hb[1]=(half_t)b0[1]; hb[2]=(half_t)b0[2]; hb[3]=(half_t)b0[3];
            hb[4]=(half_t)b1[0]; hb[5]=(half_t)b1[1]; hb[6]=(half_t)b1[2]; hb[7]=(half_t)b1[3];
            *(half8*)&sA[(t + 256 * s) * 8] = ha;
            *(half8*)&sB[(t + 256 * s) * 8] = hb;
        }
        __syncthreads();

        #pragma unroll
        for (int ks = 0; ks < 4; ++ks) {
            const int cp = 2 * ks + kg;                    // k-chunk 0..7
            const int pa0 = ((wm      + ml) * 8 + (cp ^ sw)) * 8;
            const int pa1 = ((wm + 32 + ml) * 8 + (cp ^ sw)) * 8;
            const int pb0 = ((wn      + ml) * 8 + (cp ^ sw)) * 8;
            const int pb1 = ((wn + 32 + ml) * 8 + (cp ^ sw)) * 8;
            half8 a0 = *(const half8*)&sA[pa0];
            half8 a1 = *(const half8*)&sA[pa1];
            half8 b0 = *(const half8*)&sB[pb0];
            half8 b1 = *(const half8*)&sB[pb1];
            acc[0][0] = __builtin_amdgcn_mfma_f32_32x32x16_f16(a0, b0, acc[0][0], 0, 0, 0);
            acc[0][1] = __builtin_amdgcn_mfma_f32_32x32x16_f16(a0, b1, acc[0][1], 0, 0, 0);
            acc[1][0] = __builtin_amdgcn_mfma_f32_32x32x16_f16(a1, b0, acc[1][0], 0, 0, 0);
            acc[1][1] = __builtin_amdgcn_mfma_f32_32x32x16_f16(a1, b1, acc[1][1], 0, 0, 0);
        }
        __syncthreads();
    }

    // Epilogue. 32x32 C/D layout [m74/m101]: col = lane&31,
    // row = (reg&3) + 8*(reg>>2) + 4*(lane>>5)
    const int cl = lane & 31;
    const int rb = 4 * (lane >> 5);
    #pragma unroll
    for (int j = 0; j < 2; ++j) {
        const int col = bn + wn + j * 32 + cl;
        const float bq = (float)(half_t)bias[col];   // inline bias quantize
        #pragma unroll
        for (int i = 0; i < 2; ++i) {
            #pragma unroll
            for (int r = 0; r < 16; ++r) {
                const int row = bm + wm + i * 32 + (r & 3) + 8 * (r >> 2) + rb;
                C[(long)row * N + col] = acc[i][j][r] + bq;
            }
        }
    }
}

extern "C" void kernel_launch(void* const* d_in, const int* in_sizes, int n_in,
                              void* d_out, int out_size, void* d_ws, size_t ws_size,
                              hipStream_t stream) {
    const float* x    = (const float*)d_in[0];
    const float* w    = (const float*)d_in[1];
    const float* bias = (const float*)d_in[2];
    float* out = (float*)d_out;

    const int OUT = in_sizes[2];
    const int IN  = in_sizes[1] / OUT;
    const int M   = in_sizes[0] / IN;
    const int N   = OUT, K = IN;

    dim3 grid((N / BN) * (M / BM));
    gemm_qf16_fused<<<grid, 256, 0, stream>>>(x, w, bias, out, M, N, K);
    (void)d_ws; (void)ws_size; (void)n_in; (void)out_size;
}